// Round 8
// baseline (75.660 us; speedup 1.0000x reference)
//
#include <hip/hip_runtime.h>
#include <math.h>

namespace {
constexpr int cB = 8, cS = 16, cP = 32, cN = 2048, cV = 2562;
constexpr int cK = 500;              // K_SAMPLE
constexpr int cJ = cS * cK;          // 8000 pred points per batch
constexpr int cJC = 64;              // j-chunks for global role (125 each)
constexpr int cJCH = cJ / cJC;       // 125
constexpr int cNC = 16;              // target-chunks for perslot role (128 each)
constexpr int cNCH = cN / cNC;       // 128
constexpr int cJPAD = 8192;
constexpr int cBN = cB * cN;         // 16384
constexpr float FINF = 3.402823466e+38f;

// workspace layout (float offsets)
constexpr int OFF_PRED4 = 0;                         // cB*cJ*4 = 256000
constexpr int OFF_TGT4  = 256000;                    // cBN*4 = 65536
constexpr int OFF_VBAR  = 321536;                    // 4
constexpr int OFF_OBAR  = 321540;                    // 96
constexpr int OFF_SM    = 321664;                    // 128*288 = 36864
constexpr int OFF_SC    = 358528;                    // 384
constexpr int OFF_T3    = 358912;                    // 192*cBN = 3145728 (plane-major)
constexpr int OFF_PSP   = 3504640;                   // cB*cNC*cJPAD = 1048576
constexpr int OFF_GM    = 4553216;                   // 64
constexpr int OFF_PS    = 4553280;                   // 256
} // namespace

__device__ __forceinline__ float block_sum(float v, float* red, int tid) {
  red[tid] = v;
  __syncthreads();
  for (int s = 128; s > 0; s >>= 1) {
    if (tid < s) red[tid] += red[tid + s];
    __syncthreads();
  }
  return red[0];
}

// branchless sorted top-3 insert, 3 VALU ops (min + 2x med3); exact
__device__ __forceinline__ void top3_insert(float& t0, float& t1, float& t2, float d) {
  const float n1 = __builtin_amdgcn_fmed3f(t0, t1, d);
  const float n2 = __builtin_amdgcn_fmed3f(t1, t2, d);
  t0 = fminf(t0, d);
  t1 = n1;
  t2 = n2;
}

// ---------- kernel FRONT: role-split ----------
__global__ void __launch_bounds__(256) k_front(const float* __restrict__ scales,
                                               const float* __restrict__ transforms,
                                               const float* __restrict__ pw,
                                               const float* __restrict__ offs,
                                               const float* __restrict__ verts,
                                               const float* __restrict__ target,
                                               float* __restrict__ ws) {
  const int blk = blockIdx.x;
  const int tid = threadIdx.x;
  if (blk <= cP) {
    __shared__ float red[256];
    const float* src = (blk < cP) ? (offs + blk * cV * 3) : verts;
    float acc0 = 0.f, acc1 = 0.f, acc2 = 0.f;
    for (int v = tid; v < cV; v += 256) {
      acc0 += src[v * 3 + 0];
      acc1 += src[v * 3 + 1];
      acc2 += src[v * 3 + 2];
    }
    float* dst = (blk < cP) ? (ws + OFF_OBAR + blk * 3) : (ws + OFF_VBAR);
    float a[3] = {acc0, acc1, acc2};
    for (int c = 0; c < 3; ++c) {
      float s = block_sum(a[c], red, tid);
      if (tid == 0) dst[c] = s / (float)cV;
      __syncthreads();
    }
  } else if (blk <= cP + 64) {
    const int idx = (blk - (cP + 1)) * 256 + tid;  // over cBN
    const float x = target[idx * 3 + 0];
    const float y = target[idx * 3 + 1];
    const float z = target[idx * 3 + 2];
    ((float4*)(ws + OFF_TGT4))[idx] =
        make_float4(x, y, z, 0.5f * fmaf(x, x, fmaf(y, y, z * z)));
  } else {
    const int bs = blk - (cP + 65);  // 0..127
    __shared__ float sM[cP][9];
    __shared__ float sC[3];
    __shared__ float sWT[cP][3];
    if (tid < cP) {
      const int p = tid;
      const float* t = transforms + (bs * cP + p) * 6;
      const float w = pw[bs * cP + p];
      const float sc = scales[bs];
      const float a = t[3], b = t[4], c = t[5];
      const float ca = cosf(a), sa = sinf(a);
      const float cb = cosf(b), sb = sinf(b);
      const float cg = cosf(c), sg = sinf(c);
      const float f = w * sc;
      sM[p][0] = f * (cb * cg);
      sM[p][1] = f * (-cb * sg);
      sM[p][2] = f * (sb);
      sM[p][3] = f * (ca * sg + sa * sb * cg);
      sM[p][4] = f * (ca * cg - sa * sb * sg);
      sM[p][5] = f * (-sa * cb);
      sM[p][6] = f * (sa * sg - ca * sb * cg);
      sM[p][7] = f * (sa * cg + ca * sb * sg);
      sM[p][8] = f * (ca * cb);
      sWT[p][0] = w * t[0];
      sWT[p][1] = w * t[1];
      sWT[p][2] = w * t[2];
    }
    __syncthreads();
    if (tid < 3) {
      float s = 0.f;
      for (int p = 0; p < cP; ++p) s += sWT[p][tid];
      sC[tid] = s;
    }
    __syncthreads();
    if (tid < cP * 9) ws[OFF_SM + bs * 288 + tid] = ((const float*)sM)[tid];
    if (tid < 3) ws[OFF_SC + bs * 3 + tid] = sC[tid];
    for (int k = tid; k < cK; k += 256) {
      const float x0 = verts[k * 3 + 0], x1 = verts[k * 3 + 1], x2 = verts[k * 3 + 2];
      float a0 = sC[0], a1 = sC[1], a2 = sC[2];
#pragma unroll 8
      for (int p = 0; p < cP; ++p) {
        const float* o = offs + (p * cV + k) * 3;
        const float d0 = x0 + o[0], d1 = x1 + o[1], d2 = x2 + o[2];
        a0 = fmaf(sM[p][0], d0, fmaf(sM[p][1], d1, fmaf(sM[p][2], d2, a0)));
        a1 = fmaf(sM[p][3], d0, fmaf(sM[p][4], d1, fmaf(sM[p][5], d2, a1)));
        a2 = fmaf(sM[p][6], d0, fmaf(sM[p][7], d1, fmaf(sM[p][8], d2, a2)));
      }
      ((float4*)(ws + OFF_PRED4))[bs * cK + k] =
          make_float4(a0, a1, a2, 0.5f * fmaf(a0, a0, fmaf(a1, a1, a2 * a2)));
    }
  }
}

// ---------- kernel DISTG: global role (512 blocks) ----------
// 125-pred LDS tile, 8 targets/thread, top-3 of s = hp - t.p. j-loop unroll 5.
__global__ void __launch_bounds__(256, 4) k_distg(float* __restrict__ ws) {
  __shared__ float4 sBuf[cJCH];  // 2000 B
  const int blk = blockIdx.x;
  const int tid = threadIdx.x;
  const int b = blk & 7;
  const int jc = blk >> 3;       // 0..63
  const float4* pr = (const float4*)(ws + OFF_PRED4) + b * cJ + jc * cJCH;
  if (tid < cJCH) sBuf[tid] = pr[tid];
  __syncthreads();
  const float4* tg = (const float4*)(ws + OFF_TGT4) + b * cN;
  float4 t[8];
#pragma unroll
  for (int q = 0; q < 8; ++q) t[q] = tg[tid + q * 256];
  float a0[8], a1[8], a2[8];
#pragma unroll
  for (int q = 0; q < 8; ++q) { a0[q] = FINF; a1[q] = FINF; a2[q] = FINF; }
#pragma unroll 5
  for (int j = 0; j < cJCH; ++j) {
    const float4 p = sBuf[j];
#pragma unroll
    for (int q = 0; q < 8; ++q) {
      const float s =
          fmaf(-t[q].x, p.x, fmaf(-t[q].y, p.y, fmaf(-t[q].z, p.z, p.w)));
      top3_insert(a0[q], a1[q], a2[q], s);
    }
  }
  float* plane = ws + OFF_T3 + (jc * 3) * cBN;
#pragma unroll
  for (int q = 0; q < 8; ++q) {
    const int idx = b * cN + tid + q * 256;
    plane[0 * cBN + idx] = a0[q];
    plane[1 * cBN + idx] = a1[q];
    plane[2 * cBN + idx] = a2[q];
  }
}

// ---------- kernel DISTP: perslot role (512 blocks) ----------
// 128-target LDS tile, 8 preds/thread, paired min3. n-pair loop unroll 2.
__global__ void __launch_bounds__(256, 4) k_distp(float* __restrict__ ws) {
  __shared__ float4 sT[cNCH];  // 2048 B
  const int blk = blockIdx.x;
  const int tid = threadIdx.x;
  const int jb = blk & 3;
  const int nc = (blk >> 2) & 15;
  const int b = blk >> 6;
  const float4* tg = (const float4*)(ws + OFF_TGT4) + b * cN + nc * cNCH;
  if (tid < cNCH) sT[tid] = tg[tid];
  __syncthreads();
  const float4* pr = (const float4*)(ws + OFF_PRED4) + b * cJ;
  float px[8], py[8], pz[8];
  float m[8] = {FINF, FINF, FINF, FINF, FINF, FINF, FINF, FINF};
#pragma unroll
  for (int q = 0; q < 8; ++q) {
    int j = jb * 2048 + q * 256 + tid;
    j = (j < cJ) ? j : (cJ - 1);
    const float4 p = pr[j];
    px[q] = p.x; py[q] = p.y; pz[q] = p.z;
  }
#pragma unroll 2
  for (int n2 = 0; n2 < cNCH / 2; ++n2) {
    const float4 tA = sT[2 * n2 + 0];
    const float4 tB = sT[2 * n2 + 1];
#pragma unroll
    for (int q = 0; q < 8; ++q) {
      const float sA = fmaf(-px[q], tA.x, fmaf(-py[q], tA.y, fmaf(-pz[q], tA.z, tA.w)));
      const float sB = fmaf(-px[q], tB.x, fmaf(-py[q], tB.y, fmaf(-pz[q], tB.z, tB.w)));
      m[q] = fminf(fminf(m[q], sA), sB);  // fuses to v_min3_f32
    }
  }
  float* o = ws + OFF_PSP + (b * cNC + nc) * cJPAD + jb * 2048 + tid;
#pragma unroll
  for (int q = 0; q < 8; ++q) o[q * 256] = m[q];
}

// ---------- kernel MERGE: role-split partial merges ----------
__global__ void __launch_bounds__(256) k_merge(float* __restrict__ ws) {
  __shared__ float red[256];
  const int blk = blockIdx.x;
  const int tid = threadIdx.x;
  if (blk < 64) {
    const int idx = blk * 256 + tid;  // over cBN
    const float* plane = ws + OFF_T3;
    float t0 = FINF, t1 = FINF, t2 = FINF;
#pragma unroll 8
    for (int q = 0; q < cJC * 3; ++q)
      top3_insert(t0, t1, t2, plane[q * cBN + idx]);
    const float ht = ws[OFF_TGT4 + idx * 4 + 3];
    const float d0 = fmaxf(2.f * (t0 + ht), 0.f);
    const float d1 = fmaxf(2.f * (t1 + ht), 0.f);
    const float d2 = fmaxf(2.f * (t2 + ht), 0.f);
    const float s = block_sum(d0 + d1 + d2, red, tid);
    if (tid == 0) ws[OFF_GM + blk] = s;
  } else {
    const int rb = blk - 64;
    const int b = rb >> 5;
    const int jb = rb & 31;
    const int j = jb * 256 + tid;  // 0..8191
    float contrib = 0.f;
    if (j < cJ) {
      float m = FINF;
#pragma unroll
      for (int nc = 0; nc < cNC; ++nc)
        m = fminf(m, ws[OFF_PSP + (b * cNC + nc) * cJPAD + j]);
      const float hp = ws[OFF_PRED4 + (b * cJ + j) * 4 + 3];
      contrib = fmaxf(2.f * (m + hp), 0.f);
    }
    const float s = block_sum(contrib, red, tid);
    if (tid == 0) ws[OFF_PS + b * 32 + jb] = s;
  }
}

// ---------- kernel F: centroids + repulsion + combine ----------
__global__ void __launch_bounds__(256) k_final(float* __restrict__ ws, float* __restrict__ out) {
  __shared__ float red[256];
  __shared__ float scent[cB * cS * 3];
  const int tid = threadIdx.x;
  if (tid < cB * cS) {
    const int bs = tid;
    const float* M = ws + OFF_SM + bs * 288;
    const float* vb = ws + OFF_VBAR;
    float c0 = ws[OFF_SC + bs * 3 + 0];
    float c1 = ws[OFF_SC + bs * 3 + 1];
    float c2 = ws[OFF_SC + bs * 3 + 2];
#pragma unroll 8
    for (int p = 0; p < cP; ++p) {
      const float* ob = ws + OFF_OBAR + p * 3;
      const float d0 = vb[0] + ob[0], d1 = vb[1] + ob[1], d2 = vb[2] + ob[2];
      c0 = fmaf(M[p * 9 + 0], d0, fmaf(M[p * 9 + 1], d1, fmaf(M[p * 9 + 2], d2, c0)));
      c1 = fmaf(M[p * 9 + 3], d0, fmaf(M[p * 9 + 4], d1, fmaf(M[p * 9 + 5], d2, c1)));
      c2 = fmaf(M[p * 9 + 6], d0, fmaf(M[p * 9 + 7], d1, fmaf(M[p * 9 + 8], d2, c2)));
    }
    scent[bs * 3 + 0] = c0;
    scent[bs * 3 + 1] = c1;
    scent[bs * 3 + 2] = c2;
  }
  __syncthreads();
  float acc = 0.f;
  for (int idx = tid; idx < cB * cS * cS; idx += 256) {
    const int b = idx / (cS * cS);
    const int r = idx % (cS * cS);
    const int i = r / cS, jj = r % cS;
    if (i == jj) continue;
    const float* ci = scent + (b * cS + i) * 3;
    const float* cj = scent + (b * cS + jj) * 3;
    const float dx = ci[0] - cj[0], dy = ci[1] - cj[1], dz = ci[2] - cj[2];
    const float d = sqrtf(fmaf(dx, dx, fmaf(dy, dy, dz * dz)));
    acc += expf(5.0f * fmaxf(0.5f - d, 0.0f));
  }
  const float repsum = block_sum(acc, red, tid);
  __syncthreads();
  const float gsum = block_sum((tid < 64) ? ws[OFF_GM + tid] : 0.f, red, tid);
  __syncthreads();
  const float pssum = block_sum(ws[OFF_PS + tid], red, tid);
  if (tid == 0) {
    const float global_loss = gsum / (float)(cB * cN * 3);
    const float per_slot = pssum / (float)(cB * cS * cK);
    const float rep = repsum / (float)(cB * cS * (cS - 1));
    out[0] = 0.7f * global_loss + 0.3f * per_slot + 0.2f * rep;
  }
}

extern "C" void kernel_launch(void* const* d_in, const int* in_sizes, int n_in,
                              void* d_out, int out_size, void* d_ws, size_t ws_size,
                              hipStream_t stream) {
  const float* scales     = (const float*)d_in[0];
  const float* transforms = (const float*)d_in[1];
  const float* pw         = (const float*)d_in[2];
  const float* offs       = (const float*)d_in[3];
  const float* target     = (const float*)d_in[4];
  const float* verts      = (const float*)d_in[5];
  float* out = (float*)d_out;
  float* ws = (float*)d_ws;

  k_front<<<cP + 1 + 64 + cB * cS, 256, 0, stream>>>(scales, transforms, pw, offs,
                                                     verts, target, ws);
  k_distg<<<512, 256, 0, stream>>>(ws);
  k_distp<<<512, 256, 0, stream>>>(ws);
  k_merge<<<64 + 256, 256, 0, stream>>>(ws);
  k_final<<<1, 256, 0, stream>>>(ws, out);
}

// Round 10
// 69.248 us; speedup vs baseline: 1.0926x; 1.0926x over previous
//
#include <hip/hip_runtime.h>
#include <math.h>

namespace {
constexpr int cB = 8, cS = 16, cP = 32, cN = 2048, cV = 2562;
constexpr int cK = 500;              // K_SAMPLE
constexpr int cJ = cS * cK;          // 8000 real preds per batch
constexpr int cJP = 8192;            // padded preds per batch
constexpr float FINF = 3.402823466e+38f;

// workspace layout (float offsets)
constexpr int OFF_TF   = 0;                          // target frags: cB*cN*8 = 131072
constexpr int OFF_PF   = 131072;                     // pred frags: cB*cJP*8 = 524288
constexpr int OFF_PSP  = 655360;                     // cB*32*cJP = 2097152
constexpr int OFF_T3   = 2752512;                    // cB*16*cN*4 = 2097152
constexpr int OFF_VBAR = 4849664;                    // 4
constexpr int OFF_OBAR = 4849668;                    // 96
constexpr int OFF_SM   = 4849792;                    // 36864
constexpr int OFF_SC   = 4886656;                    // 384
constexpr int OFF_GM   = 4887040;                    // 64
constexpr int OFF_PS   = 4887104;                    // 256
} // namespace

typedef __attribute__((ext_vector_type(8))) short bf16x8;
typedef __attribute__((ext_vector_type(4))) float f32x4;

__device__ __forceinline__ float block_sum(float v, float* red, int tid) {
  red[tid] = v;
  __syncthreads();
  for (int s = 128; s > 0; s >>= 1) {
    if (tid < s) red[tid] += red[tid + s];
    __syncthreads();
  }
  return red[0];
}

// branchless sorted top-3 insert, 3 VALU ops; exact
__device__ __forceinline__ void top3_insert(float& t0, float& t1, float& t2, float d) {
  const float n1 = __builtin_amdgcn_fmed3f(t0, t1, d);
  const float n2 = __builtin_amdgcn_fmed3f(t1, t2, d);
  t0 = fminf(t0, d);
  t1 = n1;
  t2 = n2;
}

__device__ __forceinline__ unsigned short f2bf(float x) {
  unsigned b = __float_as_uint(x);
  return (unsigned short)((b + 0x7FFFu + ((b >> 16) & 1u)) >> 16);
}
__device__ __forceinline__ float bf2f(unsigned short u) {
  return __uint_as_float(((unsigned)u) << 16);
}

// ---------- kernel FRONT ----------
// blk 0..32  : per-prototype mean offsets (+ mean vertex)
// blk 33..96 : target K-vector frags
// blk 97..224: pred points -> pred K-vector frags; persist sM/sC
// blk 225    : dummy pred frags (j=8000..8191), s = +30000
__global__ void __launch_bounds__(256) k_front(const float* __restrict__ scales,
                                               const float* __restrict__ transforms,
                                               const float* __restrict__ pw,
                                               const float* __restrict__ offs,
                                               const float* __restrict__ verts,
                                               const float* __restrict__ target,
                                               float* __restrict__ ws) {
  const int blk = blockIdx.x;
  const int tid = threadIdx.x;
  const unsigned short ONE = 0x3F80;
  if (blk <= cP) {
    __shared__ float red[256];
    const float* src = (blk < cP) ? (offs + blk * cV * 3) : verts;
    float acc0 = 0.f, acc1 = 0.f, acc2 = 0.f;
    for (int v = tid; v < cV; v += 256) {
      acc0 += src[v * 3 + 0];
      acc1 += src[v * 3 + 1];
      acc2 += src[v * 3 + 2];
    }
    float* dst = (blk < cP) ? (ws + OFF_OBAR + blk * 3) : (ws + OFF_VBAR);
    float a[3] = {acc0, acc1, acc2};
    for (int c = 0; c < 3; ++c) {
      float s = block_sum(a[c], red, tid);
      if (tid == 0) dst[c] = s / (float)cV;
      __syncthreads();
    }
  } else if (blk <= cP + 64) {
    const int idx = (blk - (cP + 1)) * 256 + tid;  // over cB*cN
    const float x = target[idx * 3 + 0];
    const float y = target[idx * 3 + 1];
    const float z = target[idx * 3 + 2];
    const unsigned short thx = f2bf(x), thy = f2bf(y), thz = f2bf(z);
    const unsigned short tlx = f2bf(x - bf2f(thx));
    const unsigned short tly = f2bf(y - bf2f(thy));
    const unsigned short tlz = f2bf(z - bf2f(thz));
    const float ht = 0.5f * fmaf(x, x, fmaf(y, y, z * z));
    const unsigned short hth = f2bf(ht);
    const unsigned short htl = f2bf(ht - bf2f(hth));
    unsigned short f[16] = {thx, thy, thz, thx, thy, thz, tlx, tly, tlz,
                            ONE, ONE, hth, htl, 0, 0, 0};
    float4* dst = (float4*)(ws + OFF_TF) + idx * 2;
    dst[0] = *(const float4*)&f[0];
    dst[1] = *(const float4*)&f[8];
  } else if (blk <= cP + 64 + cB * cS) {
    const int bs = blk - (cP + 65);  // 0..127
    const int b = bs >> 4, s = bs & 15;
    __shared__ float sM[cP][9];
    __shared__ float sC[3];
    __shared__ float sWT[cP][3];
    if (tid < cP) {
      const int p = tid;
      const float* t = transforms + (bs * cP + p) * 6;
      const float w = pw[bs * cP + p];
      const float sc = scales[bs];
      const float a = t[3], bb = t[4], c = t[5];
      const float ca = cosf(a), sa = sinf(a);
      const float cb = cosf(bb), sb = sinf(bb);
      const float cg = cosf(c), sg = sinf(c);
      const float f = w * sc;
      sM[p][0] = f * (cb * cg);
      sM[p][1] = f * (-cb * sg);
      sM[p][2] = f * (sb);
      sM[p][3] = f * (ca * sg + sa * sb * cg);
      sM[p][4] = f * (ca * cg - sa * sb * sg);
      sM[p][5] = f * (-sa * cb);
      sM[p][6] = f * (sa * sg - ca * sb * cg);
      sM[p][7] = f * (sa * cg + ca * sb * sg);
      sM[p][8] = f * (ca * cb);
      sWT[p][0] = w * t[0];
      sWT[p][1] = w * t[1];
      sWT[p][2] = w * t[2];
    }
    __syncthreads();
    if (tid < 3) {
      float s2 = 0.f;
      for (int p = 0; p < cP; ++p) s2 += sWT[p][tid];
      sC[tid] = s2;
    }
    __syncthreads();
    if (tid < cP * 9) ws[OFF_SM + bs * 288 + tid] = ((const float*)sM)[tid];
    if (tid < 3) ws[OFF_SC + bs * 3 + tid] = sC[tid];
    for (int k = tid; k < cK; k += 256) {
      const float x0 = verts[k * 3 + 0], x1 = verts[k * 3 + 1], x2 = verts[k * 3 + 2];
      float a0 = sC[0], a1 = sC[1], a2 = sC[2];
#pragma unroll 8
      for (int p = 0; p < cP; ++p) {
        const float* o = offs + (p * cV + k) * 3;
        const float d0 = x0 + o[0], d1 = x1 + o[1], d2 = x2 + o[2];
        a0 = fmaf(sM[p][0], d0, fmaf(sM[p][1], d1, fmaf(sM[p][2], d2, a0)));
        a1 = fmaf(sM[p][3], d0, fmaf(sM[p][4], d1, fmaf(sM[p][5], d2, a1)));
        a2 = fmaf(sM[p][6], d0, fmaf(sM[p][7], d1, fmaf(sM[p][8], d2, a2)));
      }
      const unsigned short phx = f2bf(a0), phy = f2bf(a1), phz = f2bf(a2);
      const unsigned short plx = f2bf(a0 - bf2f(phx));
      const unsigned short ply = f2bf(a1 - bf2f(phy));
      const unsigned short plz = f2bf(a2 - bf2f(phz));
      const float hp = 0.5f * fmaf(a0, a0, fmaf(a1, a1, a2 * a2));
      const unsigned short hph = f2bf(hp);
      const unsigned short hpl = f2bf(hp - bf2f(hph));
      unsigned short f[16] = {
          (unsigned short)(phx ^ 0x8000), (unsigned short)(phy ^ 0x8000),
          (unsigned short)(phz ^ 0x8000), (unsigned short)(plx ^ 0x8000),
          (unsigned short)(ply ^ 0x8000), (unsigned short)(plz ^ 0x8000),
          (unsigned short)(phx ^ 0x8000), (unsigned short)(phy ^ 0x8000),
          (unsigned short)(phz ^ 0x8000), hph, hpl, ONE, ONE, 0, 0, 0};
      float4* dst = (float4*)(ws + OFF_PF) + (b * cJP + s * cK + k) * 2;
      dst[0] = *(const float4*)&f[0];
      dst[1] = *(const float4*)&f[8];
    }
  } else {
    // dummy preds: frag zero except k9 (pairs with target ONE) = 30000
    for (int i = tid; i < cB * (cJP - cJ); i += 256) {
      const int b = i / (cJP - cJ);
      const int j = cJ + i % (cJP - cJ);
      unsigned short f[16] = {0};
      f[9] = f2bf(30000.0f);
      float4* dst = (float4*)(ws + OFF_PF) + (b * cJP + j) * 2;
      dst[0] = *(const float4*)&f[0];
      dst[1] = *(const float4*)&f[8];
    }
  }
}

// ---------- kernel DISTM: MFMA distance pass (1024 blocks) ----------
// block = (b, tg128-group, pred-eighth). Wave w: targets tgBase=tg*128+(w&1)*64,
// preds half=(w>>1) -> e*1024+half*512. Per pred-tile: 1 ds_read_b128 + 4 MFMA.
// T3 slice = e*2 + half  (16 slices per batch -- fixes R9's wave race).
__global__ void __launch_bounds__(256) k_distm(float* __restrict__ ws) {
  __shared__ unsigned short sFrag[1024 * 16 + 16];  // +16B zero block
  __shared__ float sMin[4][514];
  const int blk = blockIdx.x;
  const int tid = threadIdx.x;
  const int e = blk & 7;             // pred eighth
  const int tg = (blk >> 3) & 15;    // 128-target group
  const int b = blk >> 7;            // batch
  // stage 1024 pred frags (32 KB)
  {
    const float4* src = (const float4*)(ws + OFF_PF) + (b * cJP + e * 1024) * 2;
    float4* dst = (float4*)sFrag;
    for (int i = tid; i < 2048; i += 256) dst[i] = src[i];
    if (tid < 16) sFrag[1024 * 16 + tid] = 0;
  }
  const int w = tid >> 6, lane = tid & 63;
  const int lcol = lane & 15, lh = lane >> 4;
  for (int i = lane; i < 512; i += 64) sMin[w][i] = FINF;
  __syncthreads();

  const int half = w >> 1;                     // pred half
  const int tgBase = tg * 128 + (w & 1) * 64;  // within batch
  const f32x4 zf = {0.f, 0.f, 0.f, 0.f};
  // A-frags: 4 target tiles, fixed per wave
  bf16x8 afr0, afr1, afr2, afr3;
  {
    const float4* tf = (const float4*)(ws + OFF_TF);
    float4 z4 = make_float4(0.f, 0.f, 0.f, 0.f);
    float4 v0 = z4, v1 = z4, v2 = z4, v3 = z4;
    if (lh < 2) {
      const int base = (b * cN + tgBase + lcol) * 2 + lh;
      v0 = tf[base + 0 * 32];   // +m*16 points = m*32 float4
      v1 = tf[base + 1 * 32];
      v2 = tf[base + 2 * 32];
      v3 = tf[base + 3 * 32];
    }
    afr0 = __builtin_bit_cast(bf16x8, v0);
    afr1 = __builtin_bit_cast(bf16x8, v1);
    afr2 = __builtin_bit_cast(bf16x8, v2);
    afr3 = __builtin_bit_cast(bf16x8, v3);
  }
  float T0[4][4], T1[4][4], T2[4][4];
#pragma unroll
  for (int m = 0; m < 4; ++m)
#pragma unroll
    for (int r = 0; r < 4; ++r) { T0[m][r] = FINF; T1[m][r] = FINF; T2[m][r] = FINF; }

  int bidx = (lh < 2) ? ((half * 512 + lcol) * 16 + lh * 8) : (1024 * 16);
  const int bstep = (lh < 2) ? 256 : 0;

#pragma unroll 2
  for (int t = 0; t < 32; ++t) {
    const bf16x8 bfr = *(const bf16x8*)(&sFrag[bidx]);
    bidx += bstep;
    f32x4 c0 = __builtin_amdgcn_mfma_f32_16x16x32_bf16(afr0, bfr, zf, 0, 0, 0);
    f32x4 c1 = __builtin_amdgcn_mfma_f32_16x16x32_bf16(afr1, bfr, zf, 0, 0, 0);
    f32x4 c2 = __builtin_amdgcn_mfma_f32_16x16x32_bf16(afr2, bfr, zf, 0, 0, 0);
    f32x4 c3 = __builtin_amdgcn_mfma_f32_16x16x32_bf16(afr3, bfr, zf, 0, 0, 0);
#pragma unroll
    for (int r = 0; r < 4; ++r) top3_insert(T0[0][r], T1[0][r], T2[0][r], c0[r]);
#pragma unroll
    for (int r = 0; r < 4; ++r) top3_insert(T0[1][r], T1[1][r], T2[1][r], c1[r]);
#pragma unroll
    for (int r = 0; r < 4; ++r) top3_insert(T0[2][r], T1[2][r], T2[2][r], c2[r]);
#pragma unroll
    for (int r = 0; r < 4; ++r) top3_insert(T0[3][r], T1[3][r], T2[3][r], c3[r]);
    float v = fminf(fminf(fminf(c0[0], c0[1]), fminf(c0[2], c0[3])),
                    fminf(fminf(c1[0], c1[1]), fminf(c1[2], c1[3])));
    v = fminf(v, fminf(fminf(fminf(c2[0], c2[1]), fminf(c2[2], c2[3])),
                       fminf(fminf(c3[0], c3[1]), fminf(c3[2], c3[3]))));
    v = fminf(v, __shfl_xor(v, 16));
    v = fminf(v, __shfl_xor(v, 32));
    const int si = t * 16 + lcol;
    sMin[w][si] = fminf(sMin[w][si], v);
  }
  // per-pred min stripe -> PSP
  {
    const int slot = tg * 2 + (w & 1);
    float* dst = ws + OFF_PSP + (b * 32 + slot) * cJP + e * 1024 + half * 512;
    for (int i = lane; i < 512; i += 64) dst[i] = sMin[w][i];
  }
  // merge top3 across the 16 lanes (lcol) of each row-group
  for (int mask = 1; mask < 16; mask <<= 1) {
#pragma unroll
    for (int m = 0; m < 4; ++m)
#pragma unroll
      for (int r = 0; r < 4; ++r) {
        const float y0 = __shfl_xor(T0[m][r], mask);
        const float y1 = __shfl_xor(T1[m][r], mask);
        const float y2 = __shfl_xor(T2[m][r], mask);
        top3_insert(T0[m][r], T1[m][r], T2[m][r], y0);
        top3_insert(T0[m][r], T1[m][r], T2[m][r], y1);
        top3_insert(T0[m][r], T1[m][r], T2[m][r], y2);
      }
  }
  if (lcol == 0) {
    const int slice = e * 2 + half;  // 0..15
#pragma unroll
    for (int m = 0; m < 4; ++m)
#pragma unroll
      for (int r = 0; r < 4; ++r) {
        const int tgt = tgBase + m * 16 + lh * 4 + r;
        float* dst = ws + OFF_T3 + ((b * 16 + slice) * cN + tgt) * 4;
        dst[0] = T0[m][r];
        dst[1] = T1[m][r];
        dst[2] = T2[m][r];
      }
  }
}

// ---------- kernel MERGE ----------
// blk 0..63  : per target merge 16 slice-triples -> sum max(2C,0) -> GM
// blk 64..319: per pred min over 32 tg-slots -> max(2C,0) -> PS
__global__ void __launch_bounds__(256) k_merge(float* __restrict__ ws) {
  __shared__ float red[256];
  const int blk = blockIdx.x;
  const int tid = threadIdx.x;
  if (blk < 64) {
    const int idx = blk * 256 + tid;  // over cB*cN
    const int b = idx >> 11, n = idx & 2047;
    float t0 = FINF, t1 = FINF, t2 = FINF;
#pragma unroll
    for (int e = 0; e < 16; ++e) {
      const float* src = ws + OFF_T3 + ((b * 16 + e) * cN + n) * 4;
      top3_insert(t0, t1, t2, src[0]);
      top3_insert(t0, t1, t2, src[1]);
      top3_insert(t0, t1, t2, src[2]);
    }
    const float d0 = fmaxf(2.f * t0, 0.f);
    const float d1 = fmaxf(2.f * t1, 0.f);
    const float d2 = fmaxf(2.f * t2, 0.f);
    const float s = block_sum(d0 + d1 + d2, red, tid);
    if (tid == 0) ws[OFF_GM + blk] = s;
  } else {
    const int rb = blk - 64;
    const int b = rb >> 5;
    const int jb = rb & 31;
    const int j = jb * 256 + tid;  // 0..8191
    float contrib = 0.f;
    if (j < cJ) {
      float m = FINF;
#pragma unroll
      for (int s = 0; s < 32; ++s)
        m = fminf(m, ws[OFF_PSP + (b * 32 + s) * cJP + j]);
      contrib = fmaxf(2.f * m, 0.f);
    }
    const float s = block_sum(contrib, red, tid);
    if (tid == 0) ws[OFF_PS + b * 32 + jb] = s;
  }
}

// ---------- kernel F: centroids + repulsion + combine ----------
__global__ void __launch_bounds__(256) k_final(float* __restrict__ ws, float* __restrict__ out) {
  __shared__ float red[256];
  __shared__ float scent[cB * cS * 3];
  const int tid = threadIdx.x;
  if (tid < cB * cS) {
    const int bs = tid;
    const float* M = ws + OFF_SM + bs * 288;
    const float* vb = ws + OFF_VBAR;
    float c0 = ws[OFF_SC + bs * 3 + 0];
    float c1 = ws[OFF_SC + bs * 3 + 1];
    float c2 = ws[OFF_SC + bs * 3 + 2];
#pragma unroll 8
    for (int p = 0; p < cP; ++p) {
      const float* ob = ws + OFF_OBAR + p * 3;
      const float d0 = vb[0] + ob[0], d1 = vb[1] + ob[1], d2 = vb[2] + ob[2];
      c0 = fmaf(M[p * 9 + 0], d0, fmaf(M[p * 9 + 1], d1, fmaf(M[p * 9 + 2], d2, c0)));
      c1 = fmaf(M[p * 9 + 3], d0, fmaf(M[p * 9 + 4], d1, fmaf(M[p * 9 + 5], d2, c1)));
      c2 = fmaf(M[p * 9 + 6], d0, fmaf(M[p * 9 + 7], d1, fmaf(M[p * 9 + 8], d2, c2)));
    }
    scent[bs * 3 + 0] = c0;
    scent[bs * 3 + 1] = c1;
    scent[bs * 3 + 2] = c2;
  }
  __syncthreads();
  float acc = 0.f;
  for (int idx = tid; idx < cB * cS * cS; idx += 256) {
    const int b = idx / (cS * cS);
    const int r = idx % (cS * cS);
    const int i = r / cS, jj = r % cS;
    if (i == jj) continue;
    const float* ci = scent + (b * cS + i) * 3;
    const float* cj = scent + (b * cS + jj) * 3;
    const float dx = ci[0] - cj[0], dy = ci[1] - cj[1], dz = ci[2] - cj[2];
    const float d = sqrtf(fmaf(dx, dx, fmaf(dy, dy, dz * dz)));
    acc += expf(5.0f * fmaxf(0.5f - d, 0.0f));
  }
  const float repsum = block_sum(acc, red, tid);
  __syncthreads();
  const float gsum = block_sum((tid < 64) ? ws[OFF_GM + tid] : 0.f, red, tid);
  __syncthreads();
  const float pssum = block_sum(ws[OFF_PS + tid], red, tid);
  if (tid == 0) {
    const float global_loss = gsum / (float)(cB * cN * 3);
    const float per_slot = pssum / (float)(cB * cS * cK);
    const float rep = repsum / (float)(cB * cS * (cS - 1));
    out[0] = 0.7f * global_loss + 0.3f * per_slot + 0.2f * rep;
  }
}

extern "C" void kernel_launch(void* const* d_in, const int* in_sizes, int n_in,
                              void* d_out, int out_size, void* d_ws, size_t ws_size,
                              hipStream_t stream) {
  const float* scales     = (const float*)d_in[0];
  const float* transforms = (const float*)d_in[1];
  const float* pw         = (const float*)d_in[2];
  const float* offs       = (const float*)d_in[3];
  const float* target     = (const float*)d_in[4];
  const float* verts      = (const float*)d_in[5];
  float* out = (float*)d_out;
  float* ws = (float*)d_ws;

  k_front<<<cP + 1 + 64 + cB * cS + 1, 256, 0, stream>>>(scales, transforms, pw, offs,
                                                         verts, target, ws);
  k_distm<<<1024, 256, 0, stream>>>(ws);
  k_merge<<<64 + 256, 256, 0, stream>>>(ws);
  k_final<<<1, 256, 0, stream>>>(ws, out);
}

// Round 12
// 66.531 us; speedup vs baseline: 1.1372x; 1.0408x over previous
//
#include <hip/hip_runtime.h>
#include <math.h>

namespace {
constexpr int cB = 8, cS = 16, cP = 32, cN = 2048, cV = 2562;
constexpr int cK = 500;              // K_SAMPLE
constexpr int cJ = cS * cK;          // 8000 real preds per batch
constexpr int cJP = 8192;            // padded preds per batch
constexpr int cBN = cB * cN;         // 16384
constexpr float FINF = 3.402823466e+38f;

// workspace layout (float offsets)
constexpr int OFF_TF   = 0;                          // target frags: cB*cN*8 = 131072
constexpr int OFF_PF   = 131072;                     // pred frags: cB*cJP*8 = 524288
constexpr int OFF_PSP  = 655360;                     // cB*32*cJP = 2097152
constexpr int OFF_T3   = 2752512;                    // 48 planes * cBN = 786432
constexpr int OFF_VBAR = 3538944;                    // 4
constexpr int OFF_OBAR = 3538948;                    // 96
constexpr int OFF_SM   = 3539072;                    // 36864
constexpr int OFF_SC   = 3575936;                    // 384
constexpr int OFF_GM   = 3576320;                    // 64
constexpr int OFF_PS   = 3576384;                    // 256
} // namespace

typedef __attribute__((ext_vector_type(8))) short bf16x8;
typedef __attribute__((ext_vector_type(4))) float f32x4;

__device__ __forceinline__ float block_sum(float v, float* red, int tid) {
  red[tid] = v;
  __syncthreads();
  for (int s = 128; s > 0; s >>= 1) {
    if (tid < s) red[tid] += red[tid + s];
    __syncthreads();
  }
  return red[0];
}

// branchless sorted top-3 insert, 3 VALU ops; exact
__device__ __forceinline__ void top3_insert(float& t0, float& t1, float& t2, float d) {
  const float n1 = __builtin_amdgcn_fmed3f(t0, t1, d);
  const float n2 = __builtin_amdgcn_fmed3f(t1, t2, d);
  t0 = fminf(t0, d);
  t1 = n1;
  t2 = n2;
}

__device__ __forceinline__ unsigned short f2bf(float x) {
  unsigned b = __float_as_uint(x);
  return (unsigned short)((b + 0x7FFFu + ((b >> 16) & 1u)) >> 16);
}
__device__ __forceinline__ float bf2f(unsigned short u) {
  return __uint_as_float(((unsigned)u) << 16);
}

// ---------- kernel FRONT ----------
__global__ void __launch_bounds__(256) k_front(const float* __restrict__ scales,
                                               const float* __restrict__ transforms,
                                               const float* __restrict__ pw,
                                               const float* __restrict__ offs,
                                               const float* __restrict__ verts,
                                               const float* __restrict__ target,
                                               float* __restrict__ ws) {
  const int blk = blockIdx.x;
  const int tid = threadIdx.x;
  const unsigned short ONE = 0x3F80;
  if (blk <= cP) {
    __shared__ float red[256];
    const float* src = (blk < cP) ? (offs + blk * cV * 3) : verts;
    float acc0 = 0.f, acc1 = 0.f, acc2 = 0.f;
    for (int v = tid; v < cV; v += 256) {
      acc0 += src[v * 3 + 0];
      acc1 += src[v * 3 + 1];
      acc2 += src[v * 3 + 2];
    }
    float* dst = (blk < cP) ? (ws + OFF_OBAR + blk * 3) : (ws + OFF_VBAR);
    float a[3] = {acc0, acc1, acc2};
    for (int c = 0; c < 3; ++c) {
      float s = block_sum(a[c], red, tid);
      if (tid == 0) dst[c] = s / (float)cV;
      __syncthreads();
    }
  } else if (blk <= cP + 64) {
    const int idx = (blk - (cP + 1)) * 256 + tid;  // over cBN
    const float x = target[idx * 3 + 0];
    const float y = target[idx * 3 + 1];
    const float z = target[idx * 3 + 2];
    const unsigned short thx = f2bf(x), thy = f2bf(y), thz = f2bf(z);
    const unsigned short tlx = f2bf(x - bf2f(thx));
    const unsigned short tly = f2bf(y - bf2f(thy));
    const unsigned short tlz = f2bf(z - bf2f(thz));
    const float ht = 0.5f * fmaf(x, x, fmaf(y, y, z * z));
    const unsigned short hth = f2bf(ht);
    const unsigned short htl = f2bf(ht - bf2f(hth));
    unsigned short f[16] = {thx, thy, thz, thx, thy, thz, tlx, tly, tlz,
                            ONE, ONE, hth, htl, 0, 0, 0};
    float4* dst = (float4*)(ws + OFF_TF) + idx * 2;
    dst[0] = *(const float4*)&f[0];
    dst[1] = *(const float4*)&f[8];
  } else if (blk <= cP + 64 + cB * cS) {
    const int bs = blk - (cP + 65);  // 0..127
    const int b = bs >> 4, s = bs & 15;
    __shared__ float sM[cP][9];
    __shared__ float sC[3];
    __shared__ float sWT[cP][3];
    if (tid < cP) {
      const int p = tid;
      const float* t = transforms + (bs * cP + p) * 6;
      const float w = pw[bs * cP + p];
      const float sc = scales[bs];
      const float a = t[3], bb = t[4], c = t[5];
      const float ca = cosf(a), sa = sinf(a);
      const float cb = cosf(bb), sb = sinf(bb);
      const float cg = cosf(c), sg = sinf(c);
      const float f = w * sc;
      sM[p][0] = f * (cb * cg);
      sM[p][1] = f * (-cb * sg);
      sM[p][2] = f * (sb);
      sM[p][3] = f * (ca * sg + sa * sb * cg);
      sM[p][4] = f * (ca * cg - sa * sb * sg);
      sM[p][5] = f * (-sa * cb);
      sM[p][6] = f * (sa * sg - ca * sb * cg);
      sM[p][7] = f * (sa * cg + ca * sb * sg);
      sM[p][8] = f * (ca * cb);
      sWT[p][0] = w * t[0];
      sWT[p][1] = w * t[1];
      sWT[p][2] = w * t[2];
    }
    __syncthreads();
    if (tid < 3) {
      float s2 = 0.f;
      for (int p = 0; p < cP; ++p) s2 += sWT[p][tid];
      sC[tid] = s2;
    }
    __syncthreads();
    if (tid < cP * 9) ws[OFF_SM + bs * 288 + tid] = ((const float*)sM)[tid];
    if (tid < 3) ws[OFF_SC + bs * 3 + tid] = sC[tid];
    for (int k = tid; k < cK; k += 256) {
      const float x0 = verts[k * 3 + 0], x1 = verts[k * 3 + 1], x2 = verts[k * 3 + 2];
      float a0 = sC[0], a1 = sC[1], a2 = sC[2];
#pragma unroll 8
      for (int p = 0; p < cP; ++p) {
        const float* o = offs + (p * cV + k) * 3;
        const float d0 = x0 + o[0], d1 = x1 + o[1], d2 = x2 + o[2];
        a0 = fmaf(sM[p][0], d0, fmaf(sM[p][1], d1, fmaf(sM[p][2], d2, a0)));
        a1 = fmaf(sM[p][3], d0, fmaf(sM[p][4], d1, fmaf(sM[p][5], d2, a1)));
        a2 = fmaf(sM[p][6], d0, fmaf(sM[p][7], d1, fmaf(sM[p][8], d2, a2)));
      }
      const unsigned short phx = f2bf(a0), phy = f2bf(a1), phz = f2bf(a2);
      const unsigned short plx = f2bf(a0 - bf2f(phx));
      const unsigned short ply = f2bf(a1 - bf2f(phy));
      const unsigned short plz = f2bf(a2 - bf2f(phz));
      const float hp = 0.5f * fmaf(a0, a0, fmaf(a1, a1, a2 * a2));
      const unsigned short hph = f2bf(hp);
      const unsigned short hpl = f2bf(hp - bf2f(hph));
      unsigned short f[16] = {
          (unsigned short)(phx ^ 0x8000), (unsigned short)(phy ^ 0x8000),
          (unsigned short)(phz ^ 0x8000), (unsigned short)(plx ^ 0x8000),
          (unsigned short)(ply ^ 0x8000), (unsigned short)(plz ^ 0x8000),
          (unsigned short)(phx ^ 0x8000), (unsigned short)(phy ^ 0x8000),
          (unsigned short)(phz ^ 0x8000), hph, hpl, ONE, ONE, 0, 0, 0};
      float4* dst = (float4*)(ws + OFF_PF) + (b * cJP + s * cK + k) * 2;
      dst[0] = *(const float4*)&f[0];
      dst[1] = *(const float4*)&f[8];
    }
  } else {
    // dummy preds: frag zero except k9 (pairs with target ONE) = 30000
    for (int i = tid; i < cB * (cJP - cJ); i += 256) {
      const int b = i / (cJP - cJ);
      const int j = cJ + i % (cJP - cJ);
      unsigned short f[16] = {0};
      f[9] = f2bf(30000.0f);
      float4* dst = (float4*)(ws + OFF_PF) + (b * cJP + j) * 2;
      dst[0] = *(const float4*)&f[0];
      dst[1] = *(const float4*)&f[8];
    }
  }
}

// ---------- kernel DISTM: MFMA distance pass (2048 blocks x 128 thr) ----------
// block = (b, tg128-group, 512-pred-chunk e). Wave w (0/1): targets tg*128+w*64,
// all 512 staged preds (32 tiles). LDS 16K frag + 4K sMin = 20480 B -> 8 blk/CU.
// T3 slice = e (both waves write disjoint target rows of the SAME plane).
__global__ void __launch_bounds__(128, 4) k_distm(float* __restrict__ ws) {
  __shared__ unsigned short sFrag[512 * 16];  // 16 KB
  __shared__ float sMin[2][512];              // 4 KB
  const int blk = blockIdx.x;
  const int tid = threadIdx.x;
  const int e = blk & 15;            // 512-pred chunk
  const int tg = (blk >> 4) & 15;    // 128-target group
  const int b = blk >> 8;            // batch
  {
    const float4* src = (const float4*)(ws + OFF_PF) + (b * cJP + e * 512) * 2;
    float4* dst = (float4*)sFrag;
    for (int i = tid; i < 1024; i += 128) dst[i] = src[i];
  }
  __syncthreads();
  const int w = tid >> 6, lane = tid & 63;
  const int lcol = lane & 15, lh = lane >> 4;
  const int tgBase = tg * 128 + w * 64;
  const f32x4 zf = {0.f, 0.f, 0.f, 0.f};
  bf16x8 afr0, afr1, afr2, afr3;
  {
    const float4* tf = (const float4*)(ws + OFF_TF);
    float4 z4 = make_float4(0.f, 0.f, 0.f, 0.f);
    float4 v0 = z4, v1 = z4, v2 = z4, v3 = z4;
    if (lh < 2) {
      const int base = (b * cN + tgBase + lcol) * 2 + lh;
      v0 = tf[base + 0 * 32];
      v1 = tf[base + 1 * 32];
      v2 = tf[base + 2 * 32];
      v3 = tf[base + 3 * 32];
    }
    afr0 = __builtin_bit_cast(bf16x8, v0);
    afr1 = __builtin_bit_cast(bf16x8, v1);
    afr2 = __builtin_bit_cast(bf16x8, v2);
    afr3 = __builtin_bit_cast(bf16x8, v3);
  }
  float T0[16], T1[16], T2[16];
#pragma unroll
  for (int q = 0; q < 16; ++q) { T0[q] = FINF; T1[q] = FINF; T2[q] = FINF; }

  const int bbase = lcol * 16 + (lh & 1) * 8;
#pragma unroll 8
  for (int t = 0; t < 32; ++t) {
    const bf16x8 bfr = *(const bf16x8*)(&sFrag[t * 256 + bbase]);
    f32x4 c0 = __builtin_amdgcn_mfma_f32_16x16x32_bf16(afr0, bfr, zf, 0, 0, 0);
    f32x4 c1 = __builtin_amdgcn_mfma_f32_16x16x32_bf16(afr1, bfr, zf, 0, 0, 0);
    f32x4 c2 = __builtin_amdgcn_mfma_f32_16x16x32_bf16(afr2, bfr, zf, 0, 0, 0);
    f32x4 c3 = __builtin_amdgcn_mfma_f32_16x16x32_bf16(afr3, bfr, zf, 0, 0, 0);
#pragma unroll
    for (int r = 0; r < 4; ++r) top3_insert(T0[0 + r], T1[0 + r], T2[0 + r], c0[r]);
#pragma unroll
    for (int r = 0; r < 4; ++r) top3_insert(T0[4 + r], T1[4 + r], T2[4 + r], c1[r]);
#pragma unroll
    for (int r = 0; r < 4; ++r) top3_insert(T0[8 + r], T1[8 + r], T2[8 + r], c2[r]);
#pragma unroll
    for (int r = 0; r < 4; ++r) top3_insert(T0[12 + r], T1[12 + r], T2[12 + r], c3[r]);
    // min over 16 values (min3 triples)
    const float v0 = fminf(fminf(c0[0], c0[1]), c0[2]);
    const float v1 = fminf(fminf(c0[3], c1[0]), c1[1]);
    const float v2 = fminf(fminf(c1[2], c1[3]), c2[0]);
    const float v3 = fminf(fminf(c2[1], c2[2]), c2[3]);
    const float v4 = fminf(fminf(c3[0], c3[1]), c3[2]);
    float v = fminf(fminf(fminf(v0, v1), fminf(v2, v3)), fminf(v4, c3[3]));
    v = fminf(v, __shfl_xor(v, 16));
    v = fminf(v, __shfl_xor(v, 32));
    sMin[w][t * 16 + lcol] = v;  // 4-way same-addr write of identical value
  }
  // per-pred min stripe -> PSP (slot = tg*2 + w covers 64 targets)
  {
    float* dst = ws + OFF_PSP + (b * 32 + tg * 2 + w) * cJP + e * 512;
    for (int i = lane; i < 512; i += 64) dst[i] = sMin[w][i];
  }
  // butterfly top3 merge across the 16 lcol lanes (7-op sorted-triple merge)
#pragma unroll
  for (int mask = 1; mask < 16; mask <<= 1) {
#pragma unroll
    for (int q = 0; q < 16; ++q) {
      const float b0 = __shfl_xor(T0[q], mask);
      const float b1 = __shfl_xor(T1[q], mask);
      const float b2 = __shfl_xor(T2[q], mask);
      const float a0 = T0[q], a1 = T1[q], a2 = T2[q];
      T0[q] = fminf(a0, b0);
      T1[q] = fminf(fminf(a1, b1), fmaxf(a0, b0));
      T2[q] = fminf(fminf(a2, b2), fminf(fmaxf(a0, b1), fmaxf(a1, b0)));
    }
  }
  if (lcol == 0) {
    const int slice = e;  // 0..15; waves write disjoint target rows
#pragma unroll
    for (int m = 0; m < 4; ++m)
#pragma unroll
      for (int r = 0; r < 4; ++r) {
        const int q = m * 4 + r;
        const int idx = b * cN + tgBase + m * 16 + lh * 4 + r;
        ws[OFF_T3 + (slice * 3 + 0) * cBN + idx] = T0[q];
        ws[OFF_T3 + (slice * 3 + 1) * cBN + idx] = T1[q];
        ws[OFF_T3 + (slice * 3 + 2) * cBN + idx] = T2[q];
      }
  }
}

// ---------- kernel MERGE ----------
// blk 0..63  : per target, merge 48 planes (coalesced) -> sum max(2C,0) -> GM
// blk 64..319: per pred, min over 32 slots -> max(2C,0) -> PS
__global__ void __launch_bounds__(256) k_merge(float* __restrict__ ws) {
  __shared__ float red[256];
  const int blk = blockIdx.x;
  const int tid = threadIdx.x;
  if (blk < 64) {
    const int idx = blk * 256 + tid;  // over cBN
    const float* plane = ws + OFF_T3;
    float t0 = FINF, t1 = FINF, t2 = FINF;
#pragma unroll 8
    for (int q = 0; q < 48; ++q)
      top3_insert(t0, t1, t2, plane[q * cBN + idx]);
    const float d0 = fmaxf(2.f * t0, 0.f);
    const float d1 = fmaxf(2.f * t1, 0.f);
    const float d2 = fmaxf(2.f * t2, 0.f);
    const float s = block_sum(d0 + d1 + d2, red, tid);
    if (tid == 0) ws[OFF_GM + blk] = s;
  } else {
    const int rb = blk - 64;
    const int b = rb >> 5;
    const int jb = rb & 31;
    const int j = jb * 256 + tid;  // 0..8191
    float contrib = 0.f;
    if (j < cJ) {
      float m = FINF;
#pragma unroll
      for (int s = 0; s < 32; ++s)
        m = fminf(m, ws[OFF_PSP + (b * 32 + s) * cJP + j]);
      contrib = fmaxf(2.f * m, 0.f);
    }
    const float s = block_sum(contrib, red, tid);
    if (tid == 0) ws[OFF_PS + b * 32 + jb] = s;
  }
}

// ---------- kernel F: centroids + repulsion + combine ----------
__global__ void __launch_bounds__(256) k_final(float* __restrict__ ws, float* __restrict__ out) {
  __shared__ float red[256];
  __shared__ float scent[cB * cS * 3];
  const int tid = threadIdx.x;
  if (tid < cB * cS) {
    const int bs = tid;
    const float* M = ws + OFF_SM + bs * 288;
    const float* vb = ws + OFF_VBAR;
    float c0 = ws[OFF_SC + bs * 3 + 0];
    float c1 = ws[OFF_SC + bs * 3 + 1];
    float c2 = ws[OFF_SC + bs * 3 + 2];
#pragma unroll 8
    for (int p = 0; p < cP; ++p) {
      const float* ob = ws + OFF_OBAR + p * 3;
      const float d0 = vb[0] + ob[0], d1 = vb[1] + ob[1], d2 = vb[2] + ob[2];
      c0 = fmaf(M[p * 9 + 0], d0, fmaf(M[p * 9 + 1], d1, fmaf(M[p * 9 + 2], d2, c0)));
      c1 = fmaf(M[p * 9 + 3], d0, fmaf(M[p * 9 + 4], d1, fmaf(M[p * 9 + 5], d2, c1)));
      c2 = fmaf(M[p * 9 + 6], d0, fmaf(M[p * 9 + 7], d1, fmaf(M[p * 9 + 8], d2, c2)));
    }
    scent[bs * 3 + 0] = c0;
    scent[bs * 3 + 1] = c1;
    scent[bs * 3 + 2] = c2;
  }
  __syncthreads();
  float acc = 0.f;
  for (int idx = tid; idx < cB * cS * cS; idx += 256) {
    const int b = idx / (cS * cS);
    const int r = idx % (cS * cS);
    const int i = r / cS, jj = r % cS;
    if (i == jj) continue;
    const float* ci = scent + (b * cS + i) * 3;
    const float* cj = scent + (b * cS + jj) * 3;
    const float dx = ci[0] - cj[0], dy = ci[1] - cj[1], dz = ci[2] - cj[2];
    const float d = sqrtf(fmaf(dx, dx, fmaf(dy, dy, dz * dz)));
    acc += expf(5.0f * fmaxf(0.5f - d, 0.0f));
  }
  const float repsum = block_sum(acc, red, tid);
  __syncthreads();
  const float gsum = block_sum((tid < 64) ? ws[OFF_GM + tid] : 0.f, red, tid);
  __syncthreads();
  const float pssum = block_sum(ws[OFF_PS + tid], red, tid);
  if (tid == 0) {
    const float global_loss = gsum / (float)(cB * cN * 3);
    const float per_slot = pssum / (float)(cB * cS * cK);
    const float rep = repsum / (float)(cB * cS * (cS - 1));
    out[0] = 0.7f * global_loss + 0.3f * per_slot + 0.2f * rep;
  }
}

extern "C" void kernel_launch(void* const* d_in, const int* in_sizes, int n_in,
                              void* d_out, int out_size, void* d_ws, size_t ws_size,
                              hipStream_t stream) {
  const float* scales     = (const float*)d_in[0];
  const float* transforms = (const float*)d_in[1];
  const float* pw         = (const float*)d_in[2];
  const float* offs       = (const float*)d_in[3];
  const float* target     = (const float*)d_in[4];
  const float* verts      = (const float*)d_in[5];
  float* out = (float*)d_out;
  float* ws = (float*)d_ws;

  k_front<<<cP + 1 + 64 + cB * cS + 1, 256, 0, stream>>>(scales, transforms, pw, offs,
                                                         verts, target, ws);
  k_distm<<<2048, 128, 0, stream>>>(ws);
  k_merge<<<64 + 256, 256, 0, stream>>>(ws);
  k_final<<<1, 256, 0, stream>>>(ws, out);
}